// Round 3
// baseline (955.506 us; speedup 1.0000x reference)
//
#include <hip/hip_runtime.h>
#include <hip/hip_bf16.h>

#define T_SEQ 200
#define HDIM  256
#define EDIM  256
#define G3    768   // 3*H
#define TOUT  199   // T-1

typedef _Float16 h2_t __attribute__((ext_vector_type(2)));

static __device__ __forceinline__ float dot2acc(h2_t a, h2_t b, float c) {
  return __builtin_amdgcn_fdot2(a, b, c, false);
}

static __device__ __forceinline__ h2_t pk2(float x, float y) {
  h2_t r; r[0] = (_Float16)x; r[1] = (_Float16)y; return r;
}

// async global->LDS, 4 bytes per lane; lds base must be wave-uniform
static __device__ __forceinline__ void gload_lds4(const float* g, float* l) {
  __builtin_amdgcn_global_load_lds(
      (const __attribute__((address_space(1))) void*)g,
      (__attribute__((address_space(3))) void*)l, 4, 0, 0);
}

// fp16 h swizzle: 16B block b -> b ^ (b>>3)  (conflict-free strided b128 reads)
static __device__ __forceinline__ int swzh(int u) {
  int b  = u >> 3;
  int bp = b ^ (b >> 3);
  return (bp << 3) | (u & 7);
}

// ---------------------------------------------------------------------------
// Kernel A: gi[m][g] = sum_e (q_emb[q[m]][e]+a_emb[a[m]][e]) * w_ih[g][e]
//                      + b_ih[g] + (g<512 ? b_hh[g] : 0)      (r,z fold)
// M=12800, N=768, K=256. Grid (100,6), 256 thr, 128x128 tile, 8x8 microtile.
// (256,2): 2 blocks/CU -> 256-VGPR cap -> acc stays in registers (round-2 fix).
// ---------------------------------------------------------------------------
__global__ __launch_bounds__(256, 2) void gi_gemm_kernel(
    const int* __restrict__ questions,
    const int* __restrict__ answers,
    const float* __restrict__ q_emb,
    const float* __restrict__ a_emb,
    const float* __restrict__ w_ih,
    const float* __restrict__ b_ih,
    const float* __restrict__ b_hh,
    float* __restrict__ gi)
{
  const int tx = threadIdx.x & 15;
  const int ty = threadIdx.x >> 4;
  const int m0 = blockIdx.x * 128 + ty * 8;
  const int n0 = blockIdx.y * 128 + tx * 8;

  int qoff[8], aoff[8];
#pragma unroll
  for (int i = 0; i < 8; ++i) {
    int q = questions[m0 + i]; q = q < 0 ? 0 : q;
    int a = answers[m0 + i];   a = a < 0 ? 0 : a;
    qoff[i] = q * EDIM;
    aoff[i] = a * EDIM;
  }
  const float* wbase = w_ih + (size_t)n0 * EDIM;

  float acc[8][8] = {};
  for (int k = 0; k < EDIM; k += 4) {
    float4 av[8], bv[8];
#pragma unroll
    for (int i = 0; i < 8; ++i) {
      float4 qv = *(const float4*)(q_emb + qoff[i] + k);
      float4 ev = *(const float4*)(a_emb + aoff[i] + k);
      av[i] = make_float4(qv.x + ev.x, qv.y + ev.y, qv.z + ev.z, qv.w + ev.w);
    }
#pragma unroll
    for (int jj = 0; jj < 8; ++jj) bv[jj] = *(const float4*)(wbase + jj * EDIM + k);
#pragma unroll
    for (int i = 0; i < 8; ++i)
#pragma unroll
      for (int jj = 0; jj < 8; ++jj) {
        acc[i][jj] += av[i].x * bv[jj].x + av[i].y * bv[jj].y +
                      av[i].z * bv[jj].z + av[i].w * bv[jj].w;
      }
  }

  float bias[8];
#pragma unroll
  for (int jj = 0; jj < 8; ++jj) {
    int n = n0 + jj;
    bias[jj] = b_ih[n] + (n < 2 * HDIM ? b_hh[n] : 0.0f);  // fold b_hh for r,z only
  }

#pragma unroll
  for (int i = 0; i < 8; ++i) {
    float* dst = gi + (size_t)(m0 + i) * G3 + n0;
    float4 o0 = make_float4(acc[i][0] + bias[0], acc[i][1] + bias[1],
                            acc[i][2] + bias[2], acc[i][3] + bias[3]);
    float4 o1 = make_float4(acc[i][4] + bias[4], acc[i][5] + bias[5],
                            acc[i][6] + bias[6], acc[i][7] + bias[7]);
    *(float4*)dst = o0;
    *(float4*)(dst + 4) = o1;
  }
}

// ---------------------------------------------------------------------------
// Kernel B: sequential GRU scan. 64 blocks x 1024 thr (16 waves, 128-VGPR tier).
// Thread (g2=tid>>3, ks=tid&7) owns rows {g2+128m, m=0..5} x cols [32ks,+32)
// of W_hh as 96 fp16x2 VGPRs. h in LDS fp16 (swizzled, matvec) + fp32 (exact).
// gi rows / pred_w rows / pred_b stream in via global_load_lds (0 VGPR cost).
// ---------------------------------------------------------------------------
__global__ __launch_bounds__(1024, 4) void gru_scan_kernel(
    const int* __restrict__ questions,
    const float* __restrict__ w_hh,    // [768][256]
    const float* __restrict__ b_hh,    // [768]
    const float* __restrict__ pred_w,  // [Q+1][256]
    const float* __restrict__ pred_b,  // [Q+1]
    const float* __restrict__ gi,      // [B*T][768] (b_ih + b_hh_{r,z} folded)
    float* __restrict__ out)           // [B][199]
{
  const int b    = blockIdx.x;
  const int tid  = threadIdx.x;
  const int lane = tid & 63;
  const int wave = tid >> 6;
  const int g2   = tid >> 3;   // 0..127
  const int ks   = tid & 7;    // 32-col chunk

  __shared__ __align__(16) _Float16 hh[HDIM];   // swizzled fp16 h
  __shared__ float hf[HDIM];                    // plain fp32 h
  __shared__ float gi_buf[2][G3];
  __shared__ float pw_lds[2][HDIM];
  __shared__ float bhn_lds[HDIM];
  __shared__ float pb_lds[2];

  // --- W_hh slice -> 96 h2 VGPRs (clobbers limit the load-pressure spike) ---
  h2_t w2[6][16];
#pragma unroll
  for (int m = 0; m < 6; ++m) {
    const float* wp = w_hh + (size_t)(128 * m + g2) * HDIM + 32 * ks;
#pragma unroll
    for (int hseg = 0; hseg < 2; ++hseg) {
      float4 f0 = *(const float4*)(wp + 16 * hseg + 0);
      float4 f1 = *(const float4*)(wp + 16 * hseg + 4);
      float4 f2 = *(const float4*)(wp + 16 * hseg + 8);
      float4 f3 = *(const float4*)(wp + 16 * hseg + 12);
      w2[m][8 * hseg + 0] = pk2(f0.x, f0.y);
      w2[m][8 * hseg + 1] = pk2(f0.z, f0.w);
      w2[m][8 * hseg + 2] = pk2(f1.x, f1.y);
      w2[m][8 * hseg + 3] = pk2(f1.z, f1.w);
      w2[m][8 * hseg + 4] = pk2(f2.x, f2.y);
      w2[m][8 * hseg + 5] = pk2(f2.z, f2.w);
      w2[m][8 * hseg + 6] = pk2(f3.x, f3.y);
      w2[m][8 * hseg + 7] = pk2(f3.z, f3.w);
      asm volatile("" ::: "memory");
    }
  }

  if (tid < HDIM) {
    hf[tid] = 0.0f;
    hh[tid] = (_Float16)0.0f;
    bhn_lds[tid] = b_hh[2 * HDIM + tid];   // n-gate bias (inside r*(.))
  }

  const float* gi_b = gi + (size_t)b * T_SEQ * G3;
  const int*   q_b  = questions + b * T_SEQ;

  // prologue staging for t=0
  if (wave < 12) gload_lds4(gi_b + wave * 64 + lane, &gi_buf[0][wave * 64]);
  if (wave == 0) {
    int q0 = q_b[0]; if (q0 < 0) q0 = 0;
    const float* pr = pred_w + (size_t)q0 * HDIM;
#pragma unroll
    for (int kk = 0; kk < 4; ++kk)
      gload_lds4(pr + 64 * kk + lane, &pw_lds[0][64 * kk]);
    if (lane == 0) pb_lds[0] = pred_b[q0];
  }
  __syncthreads();

  const bool is_gate = (ks < 2);
  const int  u = g2 + 128 * ks;   // gate unit (valid for ks<2)

  int cur = 0;
  for (int t = 0; t < TOUT; ++t) {
    const int nxt = cur ^ 1;

    // phase 0: async prefetch of step t+1 state (latency hides under matvec)
    if (wave < 12)
      gload_lds4(gi_b + (size_t)(t + 1) * G3 + wave * 64 + lane,
                 &gi_buf[nxt][wave * 64]);
    if (wave == 0) {
      int qn = q_b[t + 1]; if (qn < 0) qn = 0;
      const float* pr = pred_w + (size_t)qn * HDIM;
#pragma unroll
      for (int kk = 0; kk < 4; ++kk)
        gload_lds4(pr + 64 * kk + lane, &pw_lds[nxt][64 * kk]);
      if (lane == 0) pb_lds[nxt] = pred_b[qn];
    }

    // phase 1: h fragment — 4 swizzled, conflict-free ds_read_b128
    h2_t hv[16];
#pragma unroll
    for (int c = 0; c < 4; ++c) {
      int bb = 4 * ks + c;
      int bp = bb ^ (bb >> 3);
      float4 raw = *(const float4*)((const char*)hh + (bp << 4));
      const h2_t* rp = (const h2_t*)&raw;
      hv[4 * c + 0] = rp[0]; hv[4 * c + 1] = rp[1];
      hv[4 * c + 2] = rp[2]; hv[4 * c + 3] = rp[3];
    }

    // matvec: 96 v_dot2 per thread, 6 rows x 2 chains
    float acc[6];
#pragma unroll
    for (int m = 0; m < 6; ++m) {
      float s0 = 0.0f, s1 = 0.0f;
#pragma unroll
      for (int j = 0; j < 8; ++j) {
        s0 = dot2acc(w2[m][2 * j],     hv[2 * j],     s0);
        s1 = dot2acc(w2[m][2 * j + 1], hv[2 * j + 1], s1);
      }
      acc[m] = s0 + s1;
    }
    // butterfly over the 8 ks-lanes: all lanes end with full row sums
#pragma unroll
    for (int m = 0; m < 6; ++m) {
      float s = acc[m];
      s += __shfl_xor(s, 1);
      s += __shfl_xor(s, 2);
      s += __shfl_xor(s, 4);
      acc[m] = s;
    }
    __syncthreads();  // B1: all reads of h_t complete

    // phase 2: gates (ks<2 lanes, one unit each), write h_{t+1}
    if (is_gate) {
      float sr = acc[0 + ks];
      float sz = acc[2 + ks];
      float sn = acc[4 + ks];
      float gr = gi_buf[cur][u];              // includes b_ih + b_hh (r)
      float gz = gi_buf[cur][HDIM + u];       // includes b_ih + b_hh (z)
      float gn = gi_buf[cur][2 * HDIM + u];   // includes b_ih only
      float hold = hf[u];
      float r = 1.0f / (1.0f + __expf(-(gr + sr)));
      float z = 1.0f / (1.0f + __expf(-(gz + sz)));
      float n = tanhf(gn + r * (sn + bhn_lds[u]));
      float hnew = (1.0f - z) * n + z * hold;
      hf[u] = hnew;
      hh[swzh(u)] = (_Float16)hnew;
    }
    __syncthreads();  // B2: h_{t+1} visible

    // phase 3: prediction for step t on wave 0 (others run ahead into t+1)
    if (wave == 0) {
      float s = hf[lane]       * pw_lds[cur][lane]
              + hf[64 + lane]  * pw_lds[cur][64 + lane]
              + hf[128 + lane] * pw_lds[cur][128 + lane]
              + hf[192 + lane] * pw_lds[cur][192 + lane];
      s += __shfl_xor(s, 1);
      s += __shfl_xor(s, 2);
      s += __shfl_xor(s, 4);
      s += __shfl_xor(s, 8);
      s += __shfl_xor(s, 16);
      s += __shfl_xor(s, 32);
      if (lane == 0)
        out[b * TOUT + t] = 1.0f / (1.0f + __expf(-(s + pb_lds[cur])));
    }
    cur = nxt;
  }
}

// ---------------------------------------------------------------------------
extern "C" void kernel_launch(void* const* d_in, const int* in_sizes, int n_in,
                              void* d_out, int out_size, void* d_ws, size_t ws_size,
                              hipStream_t stream) {
  const int*   questions = (const int*)d_in[1];
  const int*   answers   = (const int*)d_in[2];
  const float* q_emb     = (const float*)d_in[3];
  const float* a_emb     = (const float*)d_in[4];
  const float* w_ih      = (const float*)d_in[5];
  const float* w_hh      = (const float*)d_in[6];
  const float* b_ih      = (const float*)d_in[7];
  const float* b_hh      = (const float*)d_in[8];
  const float* pred_w    = (const float*)d_in[9];
  const float* pred_b    = (const float*)d_in[10];
  float* out = (float*)d_out;

  float* gi = (float*)d_ws;  // [64*200][768] fp32 = 39.3 MB

  gi_gemm_kernel<<<dim3(100, 6), 256, 0, stream>>>(
      questions, answers, q_emb, a_emb, w_ih, b_ih, b_hh, gi);

  gru_scan_kernel<<<64, 1024, 0, stream>>>(
      questions, w_hh, b_hh, pred_w, pred_b, gi, out);
}

// Round 4
// 928.475 us; speedup vs baseline: 1.0291x; 1.0291x over previous
//
#include <hip/hip_runtime.h>
#include <hip/hip_bf16.h>

#define T_SEQ 200
#define HDIM  256
#define EDIM  256
#define G3    768   // 3*H
#define TOUT  199   // T-1

typedef _Float16 h2_t __attribute__((ext_vector_type(2)));
typedef unsigned int u4_t __attribute__((ext_vector_type(4)));
typedef float f4_t __attribute__((ext_vector_type(4)));

static __device__ __forceinline__ float dot2acc(unsigned int w, unsigned int h, float c) {
#if __has_builtin(__builtin_amdgcn_fdot2)
  return __builtin_amdgcn_fdot2(__builtin_bit_cast(h2_t, w),
                                __builtin_bit_cast(h2_t, h), c, false);
#else
  h2_t a = __builtin_bit_cast(h2_t, w), b = __builtin_bit_cast(h2_t, h);
  return c + (float)a[0] * (float)b[0] + (float)a[1] * (float)b[1];
#endif
}

static __device__ __forceinline__ unsigned int pk(float x, float y) {
  h2_t p; p[0] = (_Float16)x; p[1] = (_Float16)y;
  return __builtin_bit_cast(unsigned int, p);
}

// ---------------------------------------------------------------------------
// Kernel A: gi[m][n] = sum_e (q_emb[q[m]][e]+a_emb[a[m]][e]) * w_ih[n][e]
//                      + b_ih[n] + (n<512 ? b_hh[n] : 0)
// M=12800, N=768, K=256. Grid (100,6), 256 thr, 128x128 tile, 8x8 microtile.
// ALL accumulators are NAMED scalars (rounds 1-3: local arrays never promote).
// ---------------------------------------------------------------------------
__global__ __launch_bounds__(256, 2) void gi_gemm_kernel(
    const int* __restrict__ questions,
    const int* __restrict__ answers,
    const float* __restrict__ q_emb,
    const float* __restrict__ a_emb,
    const float* __restrict__ w_ih,
    const float* __restrict__ b_ih,
    const float* __restrict__ b_hh,
    float* __restrict__ gi)
{
  const int tx = threadIdx.x & 15;
  const int ty = threadIdx.x >> 4;
  const int m0 = blockIdx.x * 128 + ty * 8;
  const int n0 = blockIdx.y * 128 + tx * 8;

#define QAOFF(i) \
  int qo##i, ao##i; \
  { int q_ = questions[m0 + i]; q_ = q_ < 0 ? 0 : q_; qo##i = q_ * EDIM; \
    int a_ = answers[m0 + i];   a_ = a_ < 0 ? 0 : a_; ao##i = a_ * EDIM; }
  QAOFF(0) QAOFF(1) QAOFF(2) QAOFF(3) QAOFF(4) QAOFF(5) QAOFF(6) QAOFF(7)

  const float* wb = w_ih + (size_t)n0 * EDIM;

#define DECL_ACC(i) \
  float a##i##_0=0.f,a##i##_1=0.f,a##i##_2=0.f,a##i##_3=0.f, \
        a##i##_4=0.f,a##i##_5=0.f,a##i##_6=0.f,a##i##_7=0.f;
  DECL_ACC(0) DECL_ACC(1) DECL_ACC(2) DECL_ACC(3)
  DECL_ACC(4) DECL_ACC(5) DECL_ACC(6) DECL_ACC(7)

  for (int k = 0; k < EDIM; k += 4) {
#define LOADX(i) f4_t x##i; { \
    f4_t q_ = *(const f4_t*)(q_emb + qo##i + k); \
    f4_t e_ = *(const f4_t*)(a_emb + ao##i + k); x##i = q_ + e_; }
    LOADX(0) LOADX(1) LOADX(2) LOADX(3) LOADX(4) LOADX(5) LOADX(6) LOADX(7)
#define LOADY(j) f4_t y##j = *(const f4_t*)(wb + (j) * EDIM + k);
    LOADY(0) LOADY(1) LOADY(2) LOADY(3) LOADY(4) LOADY(5) LOADY(6) LOADY(7)
#define FMA1(i,j) a##i##_##j = fmaf(x##i[3], y##j[3], fmaf(x##i[2], y##j[2], \
                    fmaf(x##i[1], y##j[1], fmaf(x##i[0], y##j[0], a##i##_##j))));
#define FMAR(i) FMA1(i,0) FMA1(i,1) FMA1(i,2) FMA1(i,3) \
                FMA1(i,4) FMA1(i,5) FMA1(i,6) FMA1(i,7)
    FMAR(0) FMAR(1) FMAR(2) FMAR(3) FMAR(4) FMAR(5) FMAR(6) FMAR(7)
  }

#define BB(j) float bb##j; { int n_ = n0 + (j); \
    bb##j = b_ih[n_] + (n_ < 2 * HDIM ? b_hh[n_] : 0.f); }
  BB(0) BB(1) BB(2) BB(3) BB(4) BB(5) BB(6) BB(7)

#define STORER(i) { float* d_ = gi + (size_t)(m0 + i) * G3 + n0; \
    f4_t o0_ = { a##i##_0+bb0, a##i##_1+bb1, a##i##_2+bb2, a##i##_3+bb3 }; \
    f4_t o1_ = { a##i##_4+bb4, a##i##_5+bb5, a##i##_6+bb6, a##i##_7+bb7 }; \
    *(f4_t*)d_ = o0_; *(f4_t*)(d_ + 4) = o1_; }
  STORER(0) STORER(1) STORER(2) STORER(3) STORER(4) STORER(5) STORER(6) STORER(7)
}

// ---------------------------------------------------------------------------
// Kernel B: sequential GRU scan. 64 blocks x 1024 thr.
// Thread (g=tid>>2, ks=tid&3): rows {g, 256+g, 512+g} x cols [64ks,64ks+64)
// of W_hh as 24 NAMED uint4 (96 VGPRs, packed fp16).
// h: fp16 in LDS (linear), fp32 h_prev in reg of gate lane.
// gi/pred_w/pred_b/q: register-prefetched 1 step ahead (double-buffered names).
// Raw s_barrier + lgkmcnt(0) only -> no vmcnt drain, prefetch spans a step.
// ---------------------------------------------------------------------------
__global__ __launch_bounds__(1024) void gru_scan_kernel(
    const int* __restrict__ questions,
    const float* __restrict__ w_hh,    // [768][256]
    const float* __restrict__ b_hh,    // [768]
    const float* __restrict__ pred_w,  // [Q+1][256]
    const float* __restrict__ pred_b,  // [Q+1]
    const float* __restrict__ gi,      // [B*T][768] (b_ih + b_hh_{r,z} folded)
    float* __restrict__ out)           // [B][199]
{
  const int b   = blockIdx.x;
  const int tid = threadIdx.x;
  const int g   = tid >> 2;   // hidden unit 0..255
  const int ks  = tid & 3;    // 64-col chunk
  const bool is_gate = (ks == 0);

  __shared__ __align__(16) _Float16 hh[HDIM];   // fp16 h, linear layout
  __shared__ float partial_lds[16];

  // ---- W_hh slice -> 24 NAMED u4 values (96 VGPRs), packed fp16 ----
  const float* wr_p = w_hh + (size_t)g * HDIM + 64 * ks;
  const float* wz_p = w_hh + (size_t)(HDIM + g) * HDIM + 64 * ks;
  const float* wn_p = w_hh + (size_t)(2 * HDIM + g) * HDIM + 64 * ks;

#define WLOAD(name, p_, r_) u4_t name; { \
    f4_t f0_ = *(const f4_t*)((p_) + 8 * (r_)); \
    f4_t f1_ = *(const f4_t*)((p_) + 8 * (r_) + 4); \
    name[0] = pk(f0_[0], f0_[1]); name[1] = pk(f0_[2], f0_[3]); \
    name[2] = pk(f1_[0], f1_[1]); name[3] = pk(f1_[2], f1_[3]); }

  WLOAD(wr0, wr_p, 0) WLOAD(wr1, wr_p, 1) WLOAD(wr2, wr_p, 2) WLOAD(wr3, wr_p, 3)
  WLOAD(wr4, wr_p, 4) WLOAD(wr5, wr_p, 5) WLOAD(wr6, wr_p, 6) WLOAD(wr7, wr_p, 7)
  WLOAD(wz0, wz_p, 0) WLOAD(wz1, wz_p, 1) WLOAD(wz2, wz_p, 2) WLOAD(wz3, wz_p, 3)
  WLOAD(wz4, wz_p, 4) WLOAD(wz5, wz_p, 5) WLOAD(wz6, wz_p, 6) WLOAD(wz7, wz_p, 7)
  WLOAD(wn0, wn_p, 0) WLOAD(wn1, wn_p, 1) WLOAD(wn2, wn_p, 2) WLOAD(wn3, wn_p, 3)
  WLOAD(wn4, wn_p, 4) WLOAD(wn5, wn_p, 5) WLOAD(wn6, wn_p, 6) WLOAD(wn7, wn_p, 7)

  float bhn = 0.f, h_prev = 0.f;
  if (is_gate) bhn = b_hh[2 * HDIM + g];

  if (tid < 32) { u4_t z_ = {0u, 0u, 0u, 0u}; *(u4_t*)((char*)hh + tid * 16) = z_; }

  const int*   q_b = questions + b * T_SEQ;
  const float* gip = gi + (size_t)b * T_SEQ * G3 + g;
  const char*  hbase = (const char*)hh + 128 * ks;

  // double-buffered prefetch state (named, no copies: loop body unrolled x2)
  float giRA = 0.f, giZA = 0.f, giNA = 0.f, pwA = 0.f, pbA = 0.f;
  float giRB = 0.f, giZB = 0.f, giNB = 0.f, pwB = 0.f, pbB = 0.f;
  int qA = 0, qB = 0;
  if (is_gate) {
    int q0 = q_b[0]; q0 = q0 < 0 ? 0 : q0;
    int q1 = q_b[1]; qB = q1 < 0 ? 0 : q1;
    giRA = gip[0]; giZA = gip[HDIM]; giNA = gip[2 * HDIM];
    pwA = pred_w[q0 * HDIM + g];
    if (tid == 0) pbA = pred_b[q0];
    gip += G3;
  }
  __syncthreads();  // prologue only (drains weight/prefetch loads too — fine)

#define RSTEP(r_) { \
    u4_t hv_ = *(const u4_t*)(hbase + 16 * r_); \
    sr = dot2acc(wr##r_[0], hv_[0], sr); sr = dot2acc(wr##r_[1], hv_[1], sr); \
    sr = dot2acc(wr##r_[2], hv_[2], sr); sr = dot2acc(wr##r_[3], hv_[3], sr); \
    sz = dot2acc(wz##r_[0], hv_[0], sz); sz = dot2acc(wz##r_[1], hv_[1], sz); \
    sz = dot2acc(wz##r_[2], hv_[2], sz); sz = dot2acc(wz##r_[3], hv_[3], sz); \
    sn = dot2acc(wn##r_[0], hv_[0], sn); sn = dot2acc(wn##r_[1], hv_[1], sn); \
    sn = dot2acc(wn##r_[2], hv_[2], sn); sn = dot2acc(wn##r_[3], hv_[3], sn); }

#define STEP(T, C, N) do { \
    /* phase 0: register-prefetch step (T)+1 into set N; q two ahead into C */ \
    if (is_gate) { \
      giR##N = gip[0]; giZ##N = gip[HDIM]; giN##N = gip[2 * HDIM]; gip += G3; \
      pw##N = pred_w[q##N * HDIM + g]; \
      if (tid == 0) pb##N = pred_b[q##N]; \
      int tq_ = (T) + 2; tq_ = tq_ > 199 ? 199 : tq_; \
      int qv_ = q_b[tq_]; q##C = qv_ < 0 ? 0 : qv_; \
    } \
    /* phase 1: matvec, 96 v_dot2 from named regs */ \
    float sr = 0.f, sz = 0.f, sn = 0.f; \
    RSTEP(0) RSTEP(1) RSTEP(2) RSTEP(3) RSTEP(4) RSTEP(5) RSTEP(6) RSTEP(7) \
    sr += __shfl_xor(sr, 1); sz += __shfl_xor(sz, 1); sn += __shfl_xor(sn, 1); \
    sr += __shfl_xor(sr, 2); sz += __shfl_xor(sz, 2); sn += __shfl_xor(sn, 2); \
    __builtin_amdgcn_sched_barrier(0); \
    __builtin_amdgcn_s_barrier();  /* B1: all h reads done */ \
    __builtin_amdgcn_sched_barrier(0); \
    /* phase 2: gates on ks==0 lanes; h update + pred partial */ \
    if (is_gate) { \
      float r_ = __fdividef(1.f, 1.f + __expf(-(giR##C + sr))); \
      float z_ = __fdividef(1.f, 1.f + __expf(-(giZ##C + sz))); \
      float e2_ = __expf(2.f * (giN##C + r_ * (sn + bhn))); \
      float n_ = 1.f - __fdividef(2.f, e2_ + 1.f); \
      h_prev = (1.f - z_) * n_ + z_ * h_prev; \
      hh[g] = (_Float16)h_prev; \
      float pp_ = h_prev * pw##C; \
      pp_ += __shfl_xor(pp_, 4);  pp_ += __shfl_xor(pp_, 8); \
      pp_ += __shfl_xor(pp_, 16); pp_ += __shfl_xor(pp_, 32); \
      if ((tid & 63) == 0) partial_lds[tid >> 6] = pp_; \
    } \
    __builtin_amdgcn_sched_barrier(0); \
    asm volatile("s_waitcnt lgkmcnt(0)" ::: "memory"); \
    __builtin_amdgcn_s_barrier();  /* B2: h_{t+1} + partials visible */ \
    __builtin_amdgcn_sched_barrier(0); \
    /* phase 3: finish prediction for step T */ \
    if (tid < 16) { \
      float v_ = partial_lds[tid]; \
      v_ += __shfl_xor(v_, 1); v_ += __shfl_xor(v_, 2); \
      v_ += __shfl_xor(v_, 4); v_ += __shfl_xor(v_, 8); \
      if (tid == 0) \
        out[b * TOUT + (T)] = __fdividef(1.f, 1.f + __expf(-(v_ + pb##C))); \
    } \
  } while (0)

  for (int T = 0; T < 198; T += 2) {
    STEP(T, A, B);
    STEP(T + 1, B, A);
  }
  STEP(198, A, B);
}

// ---------------------------------------------------------------------------
extern "C" void kernel_launch(void* const* d_in, const int* in_sizes, int n_in,
                              void* d_out, int out_size, void* d_ws, size_t ws_size,
                              hipStream_t stream) {
  const int*   questions = (const int*)d_in[1];
  const int*   answers   = (const int*)d_in[2];
  const float* q_emb     = (const float*)d_in[3];
  const float* a_emb     = (const float*)d_in[4];
  const float* w_ih      = (const float*)d_in[5];
  const float* w_hh      = (const float*)d_in[6];
  const float* b_ih      = (const float*)d_in[7];
  const float* b_hh      = (const float*)d_in[8];
  const float* pred_w    = (const float*)d_in[9];
  const float* pred_b    = (const float*)d_in[10];
  float* out = (float*)d_out;

  float* gi = (float*)d_ws;  // [64*200][768] fp32 = 39.3 MB

  gi_gemm_kernel<<<dim3(100, 6), 256, 0, stream>>>(
      questions, answers, q_emb, a_emb, w_ih, b_ih, b_hh, gi);

  gru_scan_kernel<<<64, 1024, 0, stream>>>(
      questions, w_hh, b_hh, pred_w, pred_b, gi, out);
}

// Round 5
// 689.220 us; speedup vs baseline: 1.3864x; 1.3471x over previous
//
#include <hip/hip_runtime.h>
#include <hip/hip_bf16.h>

#define T_SEQ 200
#define HDIM  256
#define EDIM  256
#define G3    768   // 3*H
#define TOUT  199   // T-1

typedef _Float16 h2_t __attribute__((ext_vector_type(2)));
typedef unsigned int u4_t __attribute__((ext_vector_type(4)));
typedef float f4_t __attribute__((ext_vector_type(4)));

static __device__ __forceinline__ float dot2acc(unsigned int w, unsigned int h, float c) {
  return __builtin_amdgcn_fdot2(__builtin_bit_cast(h2_t, w),
                                __builtin_bit_cast(h2_t, h), c, false);
}

static __device__ __forceinline__ unsigned int pk(float x, float y) {
  h2_t p; p[0] = (_Float16)x; p[1] = (_Float16)y;
  return __builtin_bit_cast(unsigned int, p);
}

// async global->LDS, 4 bytes per lane; lds base must be wave-uniform
static __device__ __forceinline__ void gload_lds4(const float* g, float* l) {
  __builtin_amdgcn_global_load_lds(
      (const __attribute__((address_space(1))) void*)g,
      (__attribute__((address_space(3))) void*)l, 4, 0, 0);
}

// ---------------------------------------------------------------------------
// Kernel A: gi[m][n] = sum_e (q_emb[q[m]][e]+a_emb[a[m]][e]) * w_ih[n][e]
//                      + b_ih[n] + (n<512 ? b_hh[n] : 0)
// M=12800, N=768, K=256. Grid (100,6), 256 thr, 128x128 tile, 8x8 microtile.
// amdgpu_waves_per_eu(2,2): PIN register budget to 256 (round-4 lesson: the
// allocator ignores launch_bounds min-waves and spills to hit 8 waves/EU).
// ---------------------------------------------------------------------------
__global__ __attribute__((amdgpu_flat_work_group_size(256, 256)))
__attribute__((amdgpu_waves_per_eu(2, 2)))
void gi_gemm_kernel(
    const int* __restrict__ questions,
    const int* __restrict__ answers,
    const float* __restrict__ q_emb,
    const float* __restrict__ a_emb,
    const float* __restrict__ w_ih,
    const float* __restrict__ b_ih,
    const float* __restrict__ b_hh,
    float* __restrict__ gi)
{
  const int tx = threadIdx.x & 15;
  const int ty = threadIdx.x >> 4;
  const int m0 = blockIdx.x * 128 + ty * 8;
  const int n0 = blockIdx.y * 128 + tx * 8;

#define QAOFF(i) \
  int qo##i, ao##i; \
  { int q_ = questions[m0 + i]; q_ = q_ < 0 ? 0 : q_; qo##i = q_ * EDIM; \
    int a_ = answers[m0 + i];   a_ = a_ < 0 ? 0 : a_; ao##i = a_ * EDIM; }
  QAOFF(0) QAOFF(1) QAOFF(2) QAOFF(3) QAOFF(4) QAOFF(5) QAOFF(6) QAOFF(7)

  const float* wb = w_ih + (size_t)n0 * EDIM;

#define DECL_ACC(i) \
  float a##i##_0=0.f,a##i##_1=0.f,a##i##_2=0.f,a##i##_3=0.f, \
        a##i##_4=0.f,a##i##_5=0.f,a##i##_6=0.f,a##i##_7=0.f;
  DECL_ACC(0) DECL_ACC(1) DECL_ACC(2) DECL_ACC(3)
  DECL_ACC(4) DECL_ACC(5) DECL_ACC(6) DECL_ACC(7)

  for (int k = 0; k < EDIM; k += 4) {
#define LOADX(i) f4_t x##i; { \
    f4_t q_ = *(const f4_t*)(q_emb + qo##i + k); \
    f4_t e_ = *(const f4_t*)(a_emb + ao##i + k); x##i = q_ + e_; }
    LOADX(0) LOADX(1) LOADX(2) LOADX(3) LOADX(4) LOADX(5) LOADX(6) LOADX(7)
#define LOADY(j) f4_t y##j = *(const f4_t*)(wb + (j) * EDIM + k);
    LOADY(0) LOADY(1) LOADY(2) LOADY(3) LOADY(4) LOADY(5) LOADY(6) LOADY(7)
#define FMA1(i,j) a##i##_##j = fmaf(x##i[3], y##j[3], fmaf(x##i[2], y##j[2], \
                    fmaf(x##i[1], y##j[1], fmaf(x##i[0], y##j[0], a##i##_##j))));
#define FMAR(i) FMA1(i,0) FMA1(i,1) FMA1(i,2) FMA1(i,3) \
                FMA1(i,4) FMA1(i,5) FMA1(i,6) FMA1(i,7)
    FMAR(0) FMAR(1) FMAR(2) FMAR(3) FMAR(4) FMAR(5) FMAR(6) FMAR(7)
  }

#define BB(j) float bb##j; { int n_ = n0 + (j); \
    bb##j = b_ih[n_] + (n_ < 2 * HDIM ? b_hh[n_] : 0.f); }
  BB(0) BB(1) BB(2) BB(3) BB(4) BB(5) BB(6) BB(7)

#define STORER(i) { float* d_ = gi + (size_t)(m0 + i) * G3 + n0; \
    f4_t o0_ = { a##i##_0+bb0, a##i##_1+bb1, a##i##_2+bb2, a##i##_3+bb3 }; \
    f4_t o1_ = { a##i##_4+bb4, a##i##_5+bb5, a##i##_6+bb6, a##i##_7+bb7 }; \
    *(f4_t*)d_ = o0_; *(f4_t*)(d_ + 4) = o1_; }
  STORER(0) STORER(1) STORER(2) STORER(3) STORER(4) STORER(5) STORER(6) STORER(7)
}

// ---------------------------------------------------------------------------
// Kernel B: sequential GRU scan. 64 blocks x 1024 thr (16 waves).
// amdgpu_waves_per_eu(4,4): PIN register budget to 128.
// Thread (g=tid>>2, ks=tid&3): W_hh rows {g, 256+g, 512+g} x cols [64ks,+64)
// as 24 NAMED uint4 (96 VGPRs packed fp16).
// h fp16 in LDS, XOR-swizzled 16B blocks (conflict-free strided b128 reads).
// gi rows + pred_w rows stream in via global_load_lds (0 VGPR); pb in regs.
// Barriers: B1 plain; B2 with counted-free vmcnt(0)+lgkmcnt(0) — the prefetch
// issued at the top of the step drains at its bottom (full-matvec in flight).
// ---------------------------------------------------------------------------
__global__ __attribute__((amdgpu_flat_work_group_size(1024, 1024)))
__attribute__((amdgpu_waves_per_eu(4, 4)))
void gru_scan_kernel(
    const int* __restrict__ questions,
    const float* __restrict__ w_hh,    // [768][256]
    const float* __restrict__ b_hh,    // [768]
    const float* __restrict__ pred_w,  // [Q+1][256]
    const float* __restrict__ pred_b,  // [Q+1]
    const float* __restrict__ gi,      // [B*T][768] (b_ih + b_hh_{r,z} folded)
    float* __restrict__ out)           // [B][199]
{
  const int b    = blockIdx.x;
  const int tid  = threadIdx.x;
  const int lane = tid & 63;
  const int wave = tid >> 6;
  const int g    = tid >> 2;   // hidden unit 0..255
  const int ks   = tid & 3;    // 64-col chunk
  const bool is_gate = (ks == 0);

  __shared__ __align__(16) _Float16 hh[HDIM];   // swizzled fp16 h (512 B)
  __shared__ float gi_buf[2][G3];
  __shared__ float pw_lds[2][HDIM];
  __shared__ float partial_lds[16];

  // ---- W_hh slice -> 24 NAMED u4 values (96 VGPRs), packed fp16 ----
  const float* wr_p = w_hh + (size_t)g * HDIM + 64 * ks;
  const float* wz_p = w_hh + (size_t)(HDIM + g) * HDIM + 64 * ks;
  const float* wn_p = w_hh + (size_t)(2 * HDIM + g) * HDIM + 64 * ks;

#define WLOAD(name, p_, r_) u4_t name; { \
    f4_t f0_ = *(const f4_t*)((p_) + 8 * (r_)); \
    f4_t f1_ = *(const f4_t*)((p_) + 8 * (r_) + 4); \
    name[0] = pk(f0_[0], f0_[1]); name[1] = pk(f0_[2], f0_[3]); \
    name[2] = pk(f1_[0], f1_[1]); name[3] = pk(f1_[2], f1_[3]); }

  WLOAD(wr0, wr_p, 0) WLOAD(wr1, wr_p, 1) WLOAD(wr2, wr_p, 2) WLOAD(wr3, wr_p, 3)
  WLOAD(wr4, wr_p, 4) WLOAD(wr5, wr_p, 5) WLOAD(wr6, wr_p, 6) WLOAD(wr7, wr_p, 7)
  WLOAD(wz0, wz_p, 0) WLOAD(wz1, wz_p, 1) WLOAD(wz2, wz_p, 2) WLOAD(wz3, wz_p, 3)
  WLOAD(wz4, wz_p, 4) WLOAD(wz5, wz_p, 5) WLOAD(wz6, wz_p, 6) WLOAD(wz7, wz_p, 7)
  WLOAD(wn0, wn_p, 0) WLOAD(wn1, wn_p, 1) WLOAD(wn2, wn_p, 2) WLOAD(wn3, wn_p, 3)
  WLOAD(wn4, wn_p, 4) WLOAD(wn5, wn_p, 5) WLOAD(wn6, wn_p, 6) WLOAD(wn7, wn_p, 7)

  float bhn = 0.f, h_prev = 0.f;
  if (is_gate) bhn = b_hh[2 * HDIM + g];

  if (tid < 32) { u4_t z_ = {0u, 0u, 0u, 0u}; *(u4_t*)((char*)hh + tid * 16) = z_; }

  const int*   q_b  = questions + b * T_SEQ;
  const float* gi_b = gi + (size_t)b * T_SEQ * G3;

  // prologue staging for t=0
  if (wave < 12) gload_lds4(gi_b + wave * 64 + lane, &gi_buf[0][wave * 64]);
  float pbA = 0.f, pbB = 0.f;
  if (wave == 0) {
    int q0 = q_b[0]; if (q0 < 0) q0 = 0;
    const float* pr = pred_w + (size_t)q0 * HDIM;
#pragma unroll
    for (int kk = 0; kk < 4; ++kk) gload_lds4(pr + 64 * kk + lane, &pw_lds[0][64 * kk]);
    if (lane == 0) pbA = pred_b[q0];
  }
  __syncthreads();   // full drain (prologue only)

  // swizzled h read base: block (8*ks + r) stored at (8*ks) | (r ^ ks)
  const char* hb2 = (const char*)hh + 128 * ks;
  const int   kx  = ks << 4;

#define RSTEP(r_) { \
    u4_t hv_ = *(const u4_t*)(hb2 + (((r_) << 4) ^ kx)); \
    sr = dot2acc(wr##r_[0], hv_[0], sr); sr = dot2acc(wr##r_[1], hv_[1], sr); \
    sr = dot2acc(wr##r_[2], hv_[2], sr); sr = dot2acc(wr##r_[3], hv_[3], sr); \
    sz = dot2acc(wz##r_[0], hv_[0], sz); sz = dot2acc(wz##r_[1], hv_[1], sz); \
    sz = dot2acc(wz##r_[2], hv_[2], sz); sz = dot2acc(wz##r_[3], hv_[3], sz); \
    sn = dot2acc(wn##r_[0], hv_[0], sn); sn = dot2acc(wn##r_[1], hv_[1], sn); \
    sn = dot2acc(wn##r_[2], hv_[2], sn); sn = dot2acc(wn##r_[3], hv_[3], sn); }

  // swizzled write slot for unit g (2B element)
  const int wblk = g >> 3;
  const int wpos = (wblk & 24) | ((wblk ^ (wblk >> 3)) & 7);
  _Float16* hwr = (_Float16*)((char*)hh + (wpos << 4) + ((g & 7) << 1));

#define STEP(T, C, N) do { \
    const int cur_ = (T) & 1; \
    /* phase 0: async prefetch of step (T)+1 into buf[cur_^1] */ \
    if (wave < 12) \
      gload_lds4(gi_b + (size_t)((T) + 1) * G3 + wave * 64 + lane, \
                 &gi_buf[cur_ ^ 1][wave * 64]); \
    if (wave == 0) { \
      int tq_ = (T) + 1; tq_ = tq_ > 199 ? 199 : tq_; \
      int qn_ = q_b[tq_]; if (qn_ < 0) qn_ = 0; \
      const float* pr_ = pred_w + (size_t)qn_ * HDIM; \
      gload_lds4(pr_ + lane,       &pw_lds[cur_ ^ 1][0]); \
      gload_lds4(pr_ + 64 + lane,  &pw_lds[cur_ ^ 1][64]); \
      gload_lds4(pr_ + 128 + lane, &pw_lds[cur_ ^ 1][128]); \
      gload_lds4(pr_ + 192 + lane, &pw_lds[cur_ ^ 1][192]); \
      if (lane == 0) pb##N = pred_b[qn_]; \
    } \
    /* phase 1: matvec, 96 v_dot2 from named regs + 8 swizzled ds_read_b128 */ \
    float sr = 0.f, sz = 0.f, sn = 0.f; \
    RSTEP(0) RSTEP(1) RSTEP(2) RSTEP(3) RSTEP(4) RSTEP(5) RSTEP(6) RSTEP(7) \
    sr += __shfl_xor(sr, 1); sz += __shfl_xor(sz, 1); sn += __shfl_xor(sn, 1); \
    sr += __shfl_xor(sr, 2); sz += __shfl_xor(sz, 2); sn += __shfl_xor(sn, 2); \
    __builtin_amdgcn_sched_barrier(0); \
    __builtin_amdgcn_s_barrier();   /* B1: all h_t reads done */ \
    __builtin_amdgcn_sched_barrier(0); \
    /* phase 2: gates on ks==0 lanes; h update + pred partial */ \
    if (is_gate) { \
      float r_ = __fdividef(1.f, 1.f + __expf(-(gi_buf[cur_][g] + sr))); \
      float z_ = __fdividef(1.f, 1.f + __expf(-(gi_buf[cur_][HDIM + g] + sz))); \
      float e2_ = __expf(2.f * (gi_buf[cur_][2 * HDIM + g] + r_ * (sn + bhn))); \
      float n_ = 1.f - __fdividef(2.f, e2_ + 1.f); \
      h_prev = (1.f - z_) * n_ + z_ * h_prev; \
      *hwr = (_Float16)h_prev; \
      float pp_ = h_prev * pw_lds[cur_][g]; \
      pp_ += __shfl_xor(pp_, 4);  pp_ += __shfl_xor(pp_, 8); \
      pp_ += __shfl_xor(pp_, 16); pp_ += __shfl_xor(pp_, 32); \
      if (lane == 0) partial_lds[wave] = pp_; \
    } \
    __builtin_amdgcn_sched_barrier(0); \
    asm volatile("s_waitcnt vmcnt(0) lgkmcnt(0)" ::: "memory"); \
    __builtin_amdgcn_s_barrier();   /* B2: h_{t+1}, partials, prefetch visible */ \
    __builtin_amdgcn_sched_barrier(0); \
    /* phase 3: finish prediction for step (T) */ \
    if (tid < 16) { \
      float v_ = partial_lds[tid]; \
      v_ += __shfl_xor(v_, 1); v_ += __shfl_xor(v_, 2); \
      v_ += __shfl_xor(v_, 4); v_ += __shfl_xor(v_, 8); \
      if (tid == 0) \
        out[b * TOUT + (T)] = __fdividef(1.f, 1.f + __expf(-(v_ + pb##C))); \
    } \
  } while (0)

  for (int T = 0; T < 198; T += 2) {
    STEP(T, A, B);
    STEP(T + 1, B, A);
  }
  STEP(198, A, B);
}

// ---------------------------------------------------------------------------
extern "C" void kernel_launch(void* const* d_in, const int* in_sizes, int n_in,
                              void* d_out, int out_size, void* d_ws, size_t ws_size,
                              hipStream_t stream) {
  const int*   questions = (const int*)d_in[1];
  const int*   answers   = (const int*)d_in[2];
  const float* q_emb     = (const float*)d_in[3];
  const float* a_emb     = (const float*)d_in[4];
  const float* w_ih      = (const float*)d_in[5];
  const float* w_hh      = (const float*)d_in[6];
  const float* b_ih      = (const float*)d_in[7];
  const float* b_hh      = (const float*)d_in[8];
  const float* pred_w    = (const float*)d_in[9];
  const float* pred_b    = (const float*)d_in[10];
  float* out = (float*)d_out;

  float* gi = (float*)d_ws;  // [64*200][768] fp32 = 39.3 MB

  gi_gemm_kernel<<<dim3(100, 6), 256, 0, stream>>>(
      questions, answers, q_emb, a_emb, w_ih, b_ih, b_hh, gi);

  gru_scan_kernel<<<64, 1024, 0, stream>>>(
      questions, w_hh, b_hh, pred_w, pred_b, gi, out);
}